// Round 1
// baseline (74.569 us; speedup 1.0000x reference)
//
#include <hip/hip_runtime.h>

// Gravity field: F[b,i,:] = G * m_i * mask_i * sum_j (m_j*mask_j) * (p_j - p_i) / max(|p_j-p_i|, 1e-4)^3
// Diagonal term is identically zero because diff == 0 exactly (no branch needed).
// max(sqrt(r2), eps) == sqrt(max(r2, eps*eps)) -> single v_rsq_f32 + clamp.
//
// This version processes TWO j-bodies per inner iteration using packed fp32
// (VOP3P v_pk_fma_f32 / v_pk_add_f32 / v_pk_mul_f32 on gfx950). The LDS tile is
// staged PAIR-TRANSPOSED so the packed operands come out of the broadcast
// ds_read_b128 as adjacent aligned VGPR pairs (no repack movs):
//   sj[2p]   = (x_{2p}, x_{2p+1}, y_{2p}, y_{2p+1})
//   sj[2p+1] = (z_{2p}, z_{2p+1}, w_{2p}, w_{2p+1})   with w = m*mask

typedef float f32x2 __attribute__((ext_vector_type(2)));
typedef float f32x4 __attribute__((ext_vector_type(4)));

#define TI 256   // bodies-i per block (= block size)
#define TJ 128   // bodies-j per block (staged in LDS)

__global__ __launch_bounds__(TI) void gravity_kernel(
    const float* __restrict__ pos,    // (B, N, 3)
    const float* __restrict__ mass,   // (B, N, 1)
    const float* __restrict__ Gp,     // (1,)
    const float* __restrict__ mask,   // (B, N)
    float* __restrict__ out,          // (B, N, 3) -- pre-zeroed
    int N, int jsplit)
{
    __shared__ f32x4 sj[TJ];          // TJ/2 pairs * 2 quads

    const int tiles_i = N / TI;
    const int per_b   = tiles_i * jsplit;
    const int bid     = blockIdx.x;
    const int b       = bid / per_b;
    const int rem     = bid - b * per_b;
    const int it      = rem / jsplit;
    const int jc      = rem - it * jsplit;
    const int tid     = threadIdx.x;
    const int i       = it * TI + tid;

    const float* posb  = pos  + (size_t)b * N * 3;
    const float* massb = mass + (size_t)b * N;
    const float* maskb = mask + (size_t)b * N;

    // Stage j-tile pair-transposed: thread p handles bodies j0=2p, j1=2p+1.
    if (tid < TJ / 2) {
        const int j0 = jc * TJ + 2 * tid;
        const float x0 = posb[j0 * 3 + 0];
        const float y0 = posb[j0 * 3 + 1];
        const float z0 = posb[j0 * 3 + 2];
        const float x1 = posb[j0 * 3 + 3];
        const float y1 = posb[j0 * 3 + 4];
        const float z1 = posb[j0 * 3 + 5];
        const float w0 = massb[j0]     * maskb[j0];
        const float w1 = massb[j0 + 1] * maskb[j0 + 1];
        sj[2 * tid]     = (f32x4){x0, x1, y0, y1};
        sj[2 * tid + 1] = (f32x4){z0, z1, w0, w1};
    }

    const float pix = posb[i * 3 + 0];
    const float piy = posb[i * 3 + 1];
    const float piz = posb[i * 3 + 2];
    const float wi  = Gp[0] * massb[i] * maskb[i];
    const f32x2 px2 = {pix, pix};
    const f32x2 py2 = {piy, piy};
    const f32x2 pz2 = {piz, piz};

    __syncthreads();

    f32x2 fx = {0.f, 0.f}, fy = {0.f, 0.f}, fz = {0.f, 0.f};
#pragma unroll 8
    for (int p = 0; p < TJ / 2; ++p) {
        const f32x4 a = sj[2 * p];        // (x0,x1,y0,y1) broadcast ds_read_b128
        const f32x4 c = sj[2 * p + 1];    // (z0,z1,w0,w1)
        const f32x2 dx = a.xy - px2;      // v_pk_add_f32 (neg)
        const f32x2 dy = a.zw - py2;
        const f32x2 dz = c.xy - pz2;
        f32x2 r2 = dz * dz;               // v_pk_mul_f32
        r2 = dy * dy + r2;                // v_pk_fma_f32 (ffp-contract)
        r2 = dx * dx + r2;
        r2.x = fmaxf(r2.x, 1e-8f);        // = (max(dist, 1e-4))^2, scalar v_max
        r2.y = fmaxf(r2.y, 1e-8f);
        f32x2 ir;
        ir.x = __builtin_amdgcn_rsqf(r2.x);   // v_rsq_f32, no OCML expansion
        ir.y = __builtin_amdgcn_rsqf(r2.y);
        const f32x2 ir3 = (ir * ir) * ir;     // 2x v_pk_mul_f32
        const f32x2 s   = c.zw * ir3;         // v_pk_mul_f32
        fx = s * dx + fx;                     // 3x v_pk_fma_f32
        fy = s * dy + fy;
        fz = s * dz + fz;
    }

    float* o = out + ((size_t)b * N + i) * 3;
    atomicAdd(&o[0], (fx.x + fx.y) * wi);
    atomicAdd(&o[1], (fy.x + fy.y) * wi);
    atomicAdd(&o[2], (fz.x + fz.y) * wi);
}

extern "C" void kernel_launch(void* const* d_in, const int* in_sizes, int n_in,
                              void* d_out, int out_size, void* d_ws, size_t ws_size,
                              hipStream_t stream)
{
    const float* pos  = (const float*)d_in[0];
    const float* mass = (const float*)d_in[1];
    const float* Gp   = (const float*)d_in[2];
    const float* mask = (const float*)d_in[3];
    float* out = (float*)d_out;

    const int N = 4096;                 // fixed problem shape
    const int B = in_sizes[3] / N;      // mask is (B, N)
    const int jsplit = N / TJ;          // 32 j-chunks per batch/i-tile

    // d_out is re-poisoned to 0xAA before every launch -> zero it (capture-safe).
    hipMemsetAsync(d_out, 0, (size_t)out_size * sizeof(float), stream);

    const int grid = B * (N / TI) * jsplit;   // 2 * 16 * 32 = 1024 blocks
    gravity_kernel<<<grid, TI, 0, stream>>>(pos, mass, Gp, mask, out, N, jsplit);
}